// Round 1
// 740.659 us; speedup vs baseline: 1.1555x; 1.1555x over previous
//
#include <hip/hip_runtime.h>
#include <hip/hip_bf16.h>

// DynamicMoE (expert-choice) MI355X. B=4,S=2048,H=1024,F=4096,E=8 -> N=8192,k=1280.
// R3: radix-select topk (was bitonic sort on 8 CUs) + split-K=2 gemm2 (640->1280 blocks).

#define H_DIM 1024
#define F_DIM 4096
#define E_NUM 8
#define N_TOK 8192
#define K_CAP 1280

typedef __bf16 bf16x8 __attribute__((ext_vector_type(8)));
typedef float f32x4 __attribute__((ext_vector_type(4)));
typedef unsigned short us4 __attribute__((ext_vector_type(4)));

__device__ __forceinline__ unsigned short f2bf(float f) {
  unsigned u = __float_as_uint(f);
  unsigned r = u + 0x7FFFu + ((u >> 16) & 1u);   // RNE
  return (unsigned short)(r >> 16);
}

__device__ __forceinline__ unsigned sortable(float f) {
  unsigned u = __float_as_uint(f);
  return (u & 0x80000000u) ? ~u : (u | 0x80000000u);
}

__device__ __forceinline__ void async_copy16(void* lds, const void* g) {
  __builtin_amdgcn_global_load_lds(
      (const __attribute__((address_space(1))) unsigned int*)g,
      (__attribute__((address_space(3))) unsigned int*)lds, 16, 0, 0);
}

// ---------------- x -> bf16 ----------------
__global__ __launch_bounds__(256) void k_cvt_x(const float* __restrict__ x,
                                               unsigned short* __restrict__ xb) {
  size_t i = ((size_t)blockIdx.x * 256 + threadIdx.x) * 8;
  float4 a = *(const float4*)(x + i);
  float4 b = *(const float4*)(x + i + 4);
  unsigned short o[8] = {f2bf(a.x), f2bf(a.y), f2bf(a.z), f2bf(a.w),
                         f2bf(b.x), f2bf(b.y), f2bf(b.z), f2bf(b.w)};
  *(uint4*)(xb + i) = *(const uint4*)o;
}

// ------------- transpose+convert: src[e][R][C] f32 -> dst[e][C][R] bf16 -----
__global__ __launch_bounds__(256) void k_transpose(const float* __restrict__ src,
                                                   unsigned short* __restrict__ dst,
                                                   int R, int C) {
  const int e = blockIdx.z;
  src += (size_t)e * R * C;
  dst += (size_t)e * R * C;
  const int c0 = blockIdx.x * 64;
  const int r0 = blockIdx.y * 64;
  __shared__ unsigned short Ls[64][72];
  const int t = threadIdx.x;
  const int mr = (t >> 4) << 2;
  const int mc = (t & 15) << 2;
  union { float4 q; float f[4]; } v[4];
#pragma unroll
  for (int rr = 0; rr < 4; ++rr)
    v[rr].q = *(const float4*)(src + (size_t)(r0 + mr + rr) * C + c0 + mc);
#pragma unroll
  for (int cc = 0; cc < 4; ++cc) {
    us4 u;
    u.x = f2bf(v[0].f[cc]); u.y = f2bf(v[1].f[cc]);
    u.z = f2bf(v[2].f[cc]); u.w = f2bf(v[3].f[cc]);
    *(us4*)&Ls[mc + cc][mr] = u;
  }
  __syncthreads();
  const int oc = t >> 2;
  const int or_ = (t & 3) * 16;
  uint4 w0 = *(const uint4*)&Ls[oc][or_];
  uint4 w1 = *(const uint4*)&Ls[oc][or_ + 8];
  unsigned short* dp = dst + (size_t)(c0 + oc) * R + r0 + or_;
  *(uint4*)dp = w0;
  *(uint4*)(dp + 8) = w1;
}

// ---------------- gate: logits[N, E], fp64 acc ----------------
__global__ __launch_bounds__(256) void k_gate(const float* __restrict__ x,
                                              const float* __restrict__ gw,
                                              float* __restrict__ logits) {
  int lane = threadIdx.x & 63;
  int wave = threadIdx.x >> 6;
  int token = blockIdx.x * 4 + wave;
  const float* xr = x + (size_t)token * H_DIM;
  double acc[E_NUM];
#pragma unroll
  for (int e = 0; e < E_NUM; ++e) acc[e] = 0.0;
  for (int i = lane; i < H_DIM; i += 64) {
    double xv = (double)xr[i];
    const float* g = gw + (size_t)i * E_NUM;
#pragma unroll
    for (int e = 0; e < E_NUM; ++e) acc[e] += xv * (double)g[e];
  }
#pragma unroll
  for (int off = 32; off > 0; off >>= 1) {
#pragma unroll
    for (int e = 0; e < E_NUM; ++e) acc[e] += __shfl_down(acc[e], off, 64);
  }
  if (lane == 0) {
#pragma unroll
    for (int e = 0; e < E_NUM; ++e)
      logits[(size_t)token * E_NUM + e] = (float)acc[e];
  }
}

// ------------- top-k per expert: 4-pass radix select --------------
// Selection semantics identical to bitonic version: all keys > thr, then
// lowest-index keys == thr to fill K_CAP (matches jax.lax.top_k tie-break set).
__global__ __launch_bounds__(1024) void k_topk(const float* __restrict__ logits,
                                               int* __restrict__ idx_out) {
  __shared__ unsigned keys[N_TOK];        // 32 KB
  __shared__ int hist[256];
  __shared__ int eq_list[128];
  __shared__ unsigned s_prefix;
  __shared__ int s_remain, s_gt, s_eqn;
  const int e = blockIdx.x;
  const int tid = threadIdx.x;

  for (int i = tid; i < N_TOK; i += 1024)
    keys[i] = sortable(logits[(size_t)i * E_NUM + e]);
  if (tid == 0) { s_prefix = 0u; s_remain = K_CAP; s_gt = 0; s_eqn = 0; }
  __syncthreads();

  // 4 radix passes, high byte -> low byte. Invariant: s_remain <= #keys matching s_prefix.
  for (int shift = 24; shift >= 0; shift -= 8) {
    if (tid < 256) hist[tid] = 0;
    __syncthreads();
    unsigned pre = s_prefix;
    unsigned mask = (shift == 24) ? 0u : (0xFFFFFFFFu << (shift + 8));
    for (int i = tid; i < N_TOK; i += 1024) {
      unsigned kk = keys[i];
      if ((kk & mask) == pre) atomicAdd(&hist[(kk >> shift) & 0xFF], 1);
    }
    __syncthreads();
    if (tid == 0) {
      int rem = s_remain;
      int b = 255;
      for (; b > 0; --b) {
        int c = hist[b];
        if (rem <= c) break;
        rem -= c;
      }
      s_prefix = pre | ((unsigned)b << shift);
      s_remain = rem;
    }
    __syncthreads();
  }

  const unsigned thr = s_prefix;   // exact K_CAP-th largest key
  for (int t = tid; t < N_TOK; t += 1024) {
    unsigned kk = keys[t];
    if (kk > thr) {
      int p = atomicAdd(&s_gt, 1);
      idx_out[e * K_CAP + p] = t;
    } else if (kk == thr) {
      int p = atomicAdd(&s_eqn, 1);
      if (p < 128) eq_list[p] = t;
    }
  }
  __syncthreads();
  if (tid == 0) {
    int gt = s_gt;
    int eqn = s_eqn < 128 ? s_eqn : 128;
    int need = K_CAP - gt;
    for (int a = 1; a < eqn; ++a) {
      int v = eq_list[a]; int b = a - 1;
      while (b >= 0 && eq_list[b] > v) { eq_list[b + 1] = eq_list[b]; --b; }
      eq_list[b + 1] = v;
    }
    for (int q = 0; q < need; ++q) idx_out[e * K_CAP + gt + q] = eq_list[q];
  }
}

// ---- GEMM1: h = silu(gather(xb) @ w1t^T), m97-style, 128x128xBK32 ----
__global__ __launch_bounds__(256) void k_gemm1(const unsigned short* __restrict__ xb,
                                               const int* __restrict__ idx,
                                               const unsigned short* __restrict__ w1t,
                                               unsigned short* __restrict__ hbuf) {
  const int m0 = blockIdx.x * 128;
  const int n0 = blockIdx.y * 128;
  const int e  = blockIdx.z;
  const int tid = threadIdx.x;
  const int wave = tid >> 6;
  const int lane = tid & 63;

  __shared__ __align__(16) unsigned short As[128 * 32];
  __shared__ __align__(16) unsigned short Bs[128 * 32];

  const int srow = wave * 32 + (lane >> 2);
  const int kcol = (lane & 3) * 8;
  const int tok0 = idx[e * K_CAP + m0 + srow];
  const int tok1 = idx[e * K_CAP + m0 + srow + 16];
  const unsigned short* ag0 = xb + (size_t)tok0 * H_DIM + kcol;
  const unsigned short* ag1 = xb + (size_t)tok1 * H_DIM + kcol;
  const unsigned short* wbase = w1t + (size_t)e * F_DIM * H_DIM;
  const unsigned short* bg0 = wbase + (size_t)(n0 + srow) * H_DIM + kcol;
  const unsigned short* bg1 = wbase + (size_t)(n0 + srow + 16) * H_DIM + kcol;
  unsigned short* la0 = As + (wave * 32) * 32;
  unsigned short* la1 = As + (wave * 32 + 16) * 32;
  unsigned short* lb0 = Bs + (wave * 32) * 32;
  unsigned short* lb1 = Bs + (wave * 32 + 16) * 32;

  const int wm = (wave & 1) * 64;
  const int wn = (wave >> 1) * 64;
  const int lrow = lane & 15;
  const int quad = lane >> 4;

  f32x4 acc[4][4];
#pragma unroll
  for (int i = 0; i < 4; ++i)
#pragma unroll
    for (int j = 0; j < 4; ++j) acc[i][j] = (f32x4){0.f, 0.f, 0.f, 0.f};

  for (int k0 = 0; k0 < H_DIM; k0 += 32) {
    __syncthreads();
    async_copy16(la0, ag0 + k0);
    async_copy16(la1, ag1 + k0);
    async_copy16(lb0, bg0 + k0);
    async_copy16(lb1, bg1 + k0);
    __syncthreads();

    bf16x8 af[4], bfr[4];
#pragma unroll
    for (int i = 0; i < 4; ++i)
      af[i] = *(const bf16x8*)&As[(wm + i * 16 + lrow) * 32 + quad * 8];
#pragma unroll
    for (int j = 0; j < 4; ++j)
      bfr[j] = *(const bf16x8*)&Bs[(wn + j * 16 + lrow) * 32 + quad * 8];
#pragma unroll
    for (int i = 0; i < 4; ++i)
#pragma unroll
      for (int j = 0; j < 4; ++j)
        acc[i][j] = __builtin_amdgcn_mfma_f32_16x16x32_bf16(af[i], bfr[j], acc[i][j], 0, 0, 0);
  }

  unsigned short* hrow = hbuf + (size_t)e * K_CAP * F_DIM;
#pragma unroll
  for (int i = 0; i < 4; ++i) {
#pragma unroll
    for (int j = 0; j < 4; ++j) {
#pragma unroll
      for (int r = 0; r < 4; ++r) {
        int gm = m0 + wm + i * 16 + quad * 4 + r;
        int gn = n0 + wn + j * 16 + lrow;
        float v = acc[i][j][r];
        float s = v / (1.f + __expf(-v));
        hrow[(size_t)gm * F_DIM + gn] = f2bf(s);
      }
    }
  }
}

// ---- GEMM2: out[tok] += h @ w2t^T, m97-style, split-K=2, scatter atomics ----
#define SPLITK 2
__global__ __launch_bounds__(256) void k_gemm2(const unsigned short* __restrict__ hbuf,
                                               const int* __restrict__ idx,
                                               const unsigned short* __restrict__ w2t,
                                               float* __restrict__ out) {
  const int m0 = blockIdx.x * 128;
  const int n0 = (blockIdx.y & 7) * 128;          // H_DIM/128 = 8 n-tiles
  const int split = blockIdx.y >> 3;
  const int e  = blockIdx.z;
  const int tid = threadIdx.x;
  const int wave = tid >> 6;
  const int lane = tid & 63;

  __shared__ __align__(16) unsigned short As[128 * 32];
  __shared__ __align__(16) unsigned short Bs[128 * 32];
  __shared__ int toks[128];
  if (tid < 128) toks[tid] = idx[e * K_CAP + m0 + tid];

  const int srow = wave * 32 + (lane >> 2);
  const int kcol = (lane & 3) * 8;
  const unsigned short* ag0 = hbuf + ((size_t)e * K_CAP + m0 + srow) * F_DIM + kcol;
  const unsigned short* ag1 = ag0 + (size_t)16 * F_DIM;
  const unsigned short* wbase = w2t + (size_t)e * H_DIM * F_DIM;
  const unsigned short* bg0 = wbase + (size_t)(n0 + srow) * F_DIM + kcol;
  const unsigned short* bg1 = bg0 + (size_t)16 * F_DIM;
  unsigned short* la0 = As + (wave * 32) * 32;
  unsigned short* la1 = As + (wave * 32 + 16) * 32;
  unsigned short* lb0 = Bs + (wave * 32) * 32;
  unsigned short* lb1 = Bs + (wave * 32 + 16) * 32;

  const int wm = (wave & 1) * 64;
  const int wn = (wave >> 1) * 64;
  const int lrow = lane & 15;
  const int quad = lane >> 4;

  f32x4 acc[4][4];
#pragma unroll
  for (int i = 0; i < 4; ++i)
#pragma unroll
    for (int j = 0; j < 4; ++j) acc[i][j] = (f32x4){0.f, 0.f, 0.f, 0.f};

  const int kbeg = split * (F_DIM / SPLITK);
  const int kend = kbeg + F_DIM / SPLITK;
  for (int k0 = kbeg; k0 < kend; k0 += 32) {
    __syncthreads();
    async_copy16(la0, ag0 + k0);
    async_copy16(la1, ag1 + k0);
    async_copy16(lb0, bg0 + k0);
    async_copy16(lb1, bg1 + k0);
    __syncthreads();

    bf16x8 af[4], bfr[4];
#pragma unroll
    for (int i = 0; i < 4; ++i)
      af[i] = *(const bf16x8*)&As[(wm + i * 16 + lrow) * 32 + quad * 8];
#pragma unroll
    for (int j = 0; j < 4; ++j)
      bfr[j] = *(const bf16x8*)&Bs[(wn + j * 16 + lrow) * 32 + quad * 8];
#pragma unroll
    for (int i = 0; i < 4; ++i)
#pragma unroll
      for (int j = 0; j < 4; ++j)
        acc[i][j] = __builtin_amdgcn_mfma_f32_16x16x32_bf16(af[i], bfr[j], acc[i][j], 0, 0, 0);
  }

#pragma unroll
  for (int i = 0; i < 4; ++i) {
#pragma unroll
    for (int r = 0; r < 4; ++r) {
      int lm = wm + i * 16 + quad * 4 + r;
      int token = toks[lm];
      float* orow = out + (size_t)token * H_DIM;
#pragma unroll
      for (int j = 0; j < 4; ++j) {
        int gn = n0 + wn + j * 16 + lrow;
        atomicAdd(&orow[gn], acc[i][j][r]);
      }
    }
  }
}

extern "C" void kernel_launch(void* const* d_in, const int* in_sizes, int n_in,
                              void* d_out, int out_size, void* d_ws, size_t ws_size,
                              hipStream_t stream) {
  const float* x  = (const float*)d_in[0];
  const float* gw = (const float*)d_in[1];
  const float* w1 = (const float*)d_in[2];
  const float* w2 = (const float*)d_in[3];
  float* out = (float*)d_out;

  char* ws = (char*)d_ws;
  float* logits = (float*)ws;                                    // 256 KB
  int* idx = (int*)(ws + 262144);                                // 40 KB
  unsigned short* xb  = (unsigned short*)(ws + 303104);          // 16 MB
  unsigned short* w1t = (unsigned short*)(ws + 17080320);        // 64 MB
  unsigned short* w2t = (unsigned short*)(ws + 84189184);        // 64 MB
  unsigned short* hbuf = (unsigned short*)(ws + 151298048);      // 80 MB

  hipMemsetAsync(d_out, 0, (size_t)out_size * sizeof(float), stream);

  k_cvt_x<<<dim3(N_TOK * H_DIM / (256 * 8)), 256, 0, stream>>>(x, xb);
  k_transpose<<<dim3(F_DIM / 64, H_DIM / 64, E_NUM), 256, 0, stream>>>(w1, w1t, H_DIM, F_DIM);
  k_transpose<<<dim3(H_DIM / 64, F_DIM / 64, E_NUM), 256, 0, stream>>>(w2, w2t, F_DIM, H_DIM);
  k_gate<<<dim3(N_TOK / 4), 256, 0, stream>>>(x, gw, logits);
  k_topk<<<dim3(E_NUM), 1024, 0, stream>>>(logits, idx);
  k_gemm1<<<dim3(K_CAP / 128, F_DIM / 128, E_NUM), 256, 0, stream>>>(xb, idx, w1t, hbuf);
  k_gemm2<<<dim3(K_CAP / 128, (H_DIM / 128) * SPLITK, E_NUM), 256, 0, stream>>>(hbuf, idx, w2t, out);
}

// Round 3
// 724.947 us; speedup vs baseline: 1.1806x; 1.0217x over previous
//
#include <hip/hip_runtime.h>
#include <hip/hip_bf16.h>

// DynamicMoE (expert-choice) MI355X. B=4,S=2048,H=1024,F=4096,E=8 -> N=8192,k=1280.
// R5 = R4 resubmit (infra failure, no counters): 2-phase prefetch (dbuf LDS,
// STAGE-next before MFMA, 1 barrier/K-step) + expert-per-XCD swizzle + gemm2 split-K=4.

#define H_DIM 1024
#define F_DIM 4096
#define E_NUM 8
#define N_TOK 8192
#define K_CAP 1280

typedef __bf16 bf16x8 __attribute__((ext_vector_type(8)));
typedef float f32x4 __attribute__((ext_vector_type(4)));
typedef unsigned short us4 __attribute__((ext_vector_type(4)));

__device__ __forceinline__ unsigned short f2bf(float f) {
  unsigned u = __float_as_uint(f);
  unsigned r = u + 0x7FFFu + ((u >> 16) & 1u);   // RNE
  return (unsigned short)(r >> 16);
}

__device__ __forceinline__ unsigned sortable(float f) {
  unsigned u = __float_as_uint(f);
  return (u & 0x80000000u) ? ~u : (u | 0x80000000u);
}

__device__ __forceinline__ void async_copy16(void* lds, const void* g) {
  __builtin_amdgcn_global_load_lds(
      (const __attribute__((address_space(1))) unsigned int*)g,
      (__attribute__((address_space(3))) unsigned int*)lds, 16, 0, 0);
}

// ---------------- x -> bf16 ----------------
__global__ __launch_bounds__(256) void k_cvt_x(const float* __restrict__ x,
                                               unsigned short* __restrict__ xb) {
  size_t i = ((size_t)blockIdx.x * 256 + threadIdx.x) * 8;
  float4 a = *(const float4*)(x + i);
  float4 b = *(const float4*)(x + i + 4);
  unsigned short o[8] = {f2bf(a.x), f2bf(a.y), f2bf(a.z), f2bf(a.w),
                         f2bf(b.x), f2bf(b.y), f2bf(b.z), f2bf(b.w)};
  *(uint4*)(xb + i) = *(const uint4*)o;
}

// ------------- transpose+convert: src[e][R][C] f32 -> dst[e][C][R] bf16 -----
__global__ __launch_bounds__(256) void k_transpose(const float* __restrict__ src,
                                                   unsigned short* __restrict__ dst,
                                                   int R, int C) {
  const int e = blockIdx.z;
  src += (size_t)e * R * C;
  dst += (size_t)e * R * C;
  const int c0 = blockIdx.x * 64;
  const int r0 = blockIdx.y * 64;
  __shared__ unsigned short Ls[64][72];
  const int t = threadIdx.x;
  const int mr = (t >> 4) << 2;
  const int mc = (t & 15) << 2;
  union { float4 q; float f[4]; } v[4];
#pragma unroll
  for (int rr = 0; rr < 4; ++rr)
    v[rr].q = *(const float4*)(src + (size_t)(r0 + mr + rr) * C + c0 + mc);
#pragma unroll
  for (int cc = 0; cc < 4; ++cc) {
    us4 u;
    u.x = f2bf(v[0].f[cc]); u.y = f2bf(v[1].f[cc]);
    u.z = f2bf(v[2].f[cc]); u.w = f2bf(v[3].f[cc]);
    *(us4*)&Ls[mc + cc][mr] = u;
  }
  __syncthreads();
  const int oc = t >> 2;
  const int or_ = (t & 3) * 16;
  uint4 w0 = *(const uint4*)&Ls[oc][or_];
  uint4 w1 = *(const uint4*)&Ls[oc][or_ + 8];
  unsigned short* dp = dst + (size_t)(c0 + oc) * R + r0 + or_;
  *(uint4*)dp = w0;
  *(uint4*)(dp + 8) = w1;
}

// ---------------- gate: logits[N, E], fp64 acc ----------------
__global__ __launch_bounds__(256) void k_gate(const float* __restrict__ x,
                                              const float* __restrict__ gw,
                                              float* __restrict__ logits) {
  int lane = threadIdx.x & 63;
  int wave = threadIdx.x >> 6;
  int token = blockIdx.x * 4 + wave;
  const float* xr = x + (size_t)token * H_DIM;
  double acc[E_NUM];
#pragma unroll
  for (int e = 0; e < E_NUM; ++e) acc[e] = 0.0;
  for (int i = lane; i < H_DIM; i += 64) {
    double xv = (double)xr[i];
    const float* g = gw + (size_t)i * E_NUM;
#pragma unroll
    for (int e = 0; e < E_NUM; ++e) acc[e] += xv * (double)g[e];
  }
#pragma unroll
  for (int off = 32; off > 0; off >>= 1) {
#pragma unroll
    for (int e = 0; e < E_NUM; ++e) acc[e] += __shfl_down(acc[e], off, 64);
  }
  if (lane == 0) {
#pragma unroll
    for (int e = 0; e < E_NUM; ++e)
      logits[(size_t)token * E_NUM + e] = (float)acc[e];
  }
}

// ------------- top-k per expert: 4-pass radix select --------------
__global__ __launch_bounds__(1024) void k_topk(const float* __restrict__ logits,
                                               int* __restrict__ idx_out) {
  __shared__ unsigned keys[N_TOK];        // 32 KB
  __shared__ int hist[256];
  __shared__ int eq_list[128];
  __shared__ unsigned s_prefix;
  __shared__ int s_remain, s_gt, s_eqn;
  const int e = blockIdx.x;
  const int tid = threadIdx.x;

  for (int i = tid; i < N_TOK; i += 1024)
    keys[i] = sortable(logits[(size_t)i * E_NUM + e]);
  if (tid == 0) { s_prefix = 0u; s_remain = K_CAP; s_gt = 0; s_eqn = 0; }
  __syncthreads();

  for (int shift = 24; shift >= 0; shift -= 8) {
    if (tid < 256) hist[tid] = 0;
    __syncthreads();
    unsigned pre = s_prefix;
    unsigned mask = (shift == 24) ? 0u : (0xFFFFFFFFu << (shift + 8));
    for (int i = tid; i < N_TOK; i += 1024) {
      unsigned kk = keys[i];
      if ((kk & mask) == pre) atomicAdd(&hist[(kk >> shift) & 0xFF], 1);
    }
    __syncthreads();
    if (tid == 0) {
      int rem = s_remain;
      int b = 255;
      for (; b > 0; --b) {
        int c = hist[b];
        if (rem <= c) break;
        rem -= c;
      }
      s_prefix = pre | ((unsigned)b << shift);
      s_remain = rem;
    }
    __syncthreads();
  }

  const unsigned thr = s_prefix;   // exact K_CAP-th largest key
  for (int t = tid; t < N_TOK; t += 1024) {
    unsigned kk = keys[t];
    if (kk > thr) {
      int p = atomicAdd(&s_gt, 1);
      idx_out[e * K_CAP + p] = t;
    } else if (kk == thr) {
      int p = atomicAdd(&s_eqn, 1);
      if (p < 128) eq_list[p] = t;
    }
  }
  __syncthreads();
  if (tid == 0) {
    int gt = s_gt;
    int eqn = s_eqn < 128 ? s_eqn : 128;
    int need = K_CAP - gt;
    for (int a = 1; a < eqn; ++a) {
      int v = eq_list[a]; int b = a - 1;
      while (b >= 0 && eq_list[b] > v) { eq_list[b + 1] = eq_list[b]; --b; }
      eq_list[b + 1] = v;
    }
    for (int q = 0; q < need; ++q) idx_out[e * K_CAP + gt + q] = eq_list[q];
  }
}

// ---- GEMM1: h = silu(gather(xb) @ w1t^T), 128x128xBK32, 2-phase dbuf ----
// 1D grid 2560: e = bid&7 (expert-per-XCD), within: ny-major, m-fastest.
__global__ __launch_bounds__(256) void k_gemm1(const unsigned short* __restrict__ xb,
                                               const int* __restrict__ idxp,
                                               const unsigned short* __restrict__ w1t,
                                               unsigned short* __restrict__ hbuf) {
  const int bid = blockIdx.x;
  const int e   = bid & 7;
  const int lid = bid >> 3;            // 0..319
  const int ny  = lid / 10;            // 0..31
  const int mi  = lid - ny * 10;       // 0..9
  const int m0  = mi * 128;
  const int n0  = ny * 128;
  const int tid = threadIdx.x;
  const int wave = tid >> 6;
  const int lane = tid & 63;

  __shared__ __align__(16) unsigned short As[2 * 128 * 32];
  __shared__ __align__(16) unsigned short Bs[2 * 128 * 32];

  const int srow = wave * 32 + (lane >> 2);
  const int kcol = (lane & 3) * 8;
  const int tok0 = idxp[e * K_CAP + m0 + srow];
  const int tok1 = idxp[e * K_CAP + m0 + srow + 16];
  const unsigned short* ag0 = xb + (size_t)tok0 * H_DIM + kcol;
  const unsigned short* ag1 = xb + (size_t)tok1 * H_DIM + kcol;
  const unsigned short* wbase = w1t + (size_t)e * F_DIM * H_DIM;
  const unsigned short* bg0 = wbase + (size_t)(n0 + srow) * H_DIM + kcol;
  const unsigned short* bg1 = wbase + (size_t)(n0 + srow + 16) * H_DIM + kcol;
  const int woff0 = (wave * 32) * 32;        // wave-uniform LDS short-offsets
  const int woff1 = (wave * 32 + 16) * 32;

#define STAGE_G(buf, kk)                                   \
  do {                                                     \
    async_copy16(&As[(buf) * 4096 + woff0], ag0 + (kk));   \
    async_copy16(&As[(buf) * 4096 + woff1], ag1 + (kk));   \
    async_copy16(&Bs[(buf) * 4096 + woff0], bg0 + (kk));   \
    async_copy16(&Bs[(buf) * 4096 + woff1], bg1 + (kk));   \
  } while (0)

  const int wm = (wave & 1) * 64;
  const int wn = (wave >> 1) * 64;
  const int lrow = lane & 15;
  const int quad = lane >> 4;

  f32x4 acc[4][4];
#pragma unroll
  for (int i = 0; i < 4; ++i)
#pragma unroll
    for (int j = 0; j < 4; ++j) acc[i][j] = (f32x4){0.f, 0.f, 0.f, 0.f};

  STAGE_G(0, 0);
  __syncthreads();                      // drains vmcnt: buf0 ready
  int cur = 0;
  for (int k0 = 0; k0 < H_DIM; k0 += 32) {
    if (k0 + 32 < H_DIM) STAGE_G(cur ^ 1, k0 + 32);   // prefetch overlaps MFMA

    bf16x8 af[4], bfr[4];
#pragma unroll
    for (int i = 0; i < 4; ++i)
      af[i] = *(const bf16x8*)&As[cur * 4096 + (wm + i * 16 + lrow) * 32 + quad * 8];
#pragma unroll
    for (int j = 0; j < 4; ++j)
      bfr[j] = *(const bf16x8*)&Bs[cur * 4096 + (wn + j * 16 + lrow) * 32 + quad * 8];
#pragma unroll
    for (int i = 0; i < 4; ++i)
#pragma unroll
      for (int j = 0; j < 4; ++j)
        acc[i][j] = __builtin_amdgcn_mfma_f32_16x16x32_bf16(af[i], bfr[j], acc[i][j], 0, 0, 0);

    __syncthreads();                    // drains prefetch vmcnt + read fence
    cur ^= 1;
  }

  unsigned short* hrow = hbuf + (size_t)e * K_CAP * F_DIM;
#pragma unroll
  for (int i = 0; i < 4; ++i) {
#pragma unroll
    for (int j = 0; j < 4; ++j) {
#pragma unroll
      for (int r = 0; r < 4; ++r) {
        int gm = m0 + wm + i * 16 + quad * 4 + r;
        int gn = n0 + wn + j * 16 + lrow;
        float v = acc[i][j][r];
        float s = v / (1.f + __expf(-v));
        hrow[(size_t)gm * F_DIM + gn] = f2bf(s);
      }
    }
  }
}

// ---- GEMM2: out[tok] += h @ w2t^T, split-K=4, 2-phase dbuf, scatter atomics ----
#define SPLITK 4
__global__ __launch_bounds__(256) void k_gemm2(const unsigned short* __restrict__ hbuf,
                                               const int* __restrict__ idxp,
                                               const unsigned short* __restrict__ w2t,
                                               float* __restrict__ out) {
  const int bid = blockIdx.x;
  const int e   = bid & 7;
  const int lid = bid >> 3;            // 0..319
  const int split = lid / 80;          // 0..3
  const int r2  = lid - split * 80;
  const int ny  = r2 / 10;             // 0..7
  const int mi  = r2 - ny * 10;        // 0..9
  const int m0  = mi * 128;
  const int n0  = ny * 128;
  const int tid = threadIdx.x;
  const int wave = tid >> 6;
  const int lane = tid & 63;

  __shared__ __align__(16) unsigned short As[2 * 128 * 32];
  __shared__ __align__(16) unsigned short Bs[2 * 128 * 32];
  __shared__ int toks[128];
  if (tid < 128) toks[tid] = idxp[e * K_CAP + m0 + tid];

  const int srow = wave * 32 + (lane >> 2);
  const int kcol = (lane & 3) * 8;
  const unsigned short* ag0 = hbuf + ((size_t)e * K_CAP + m0 + srow) * F_DIM + kcol;
  const unsigned short* ag1 = ag0 + (size_t)16 * F_DIM;
  const unsigned short* wbase = w2t + (size_t)e * H_DIM * F_DIM;
  const unsigned short* bg0 = wbase + (size_t)(n0 + srow) * F_DIM + kcol;
  const unsigned short* bg1 = bg0 + (size_t)16 * F_DIM;
  const int woff0 = (wave * 32) * 32;
  const int woff1 = (wave * 32 + 16) * 32;

  const int wm = (wave & 1) * 64;
  const int wn = (wave >> 1) * 64;
  const int lrow = lane & 15;
  const int quad = lane >> 4;

  f32x4 acc[4][4];
#pragma unroll
  for (int i = 0; i < 4; ++i)
#pragma unroll
    for (int j = 0; j < 4; ++j) acc[i][j] = (f32x4){0.f, 0.f, 0.f, 0.f};

  const int kbeg = split * (F_DIM / SPLITK);
  const int kend = kbeg + F_DIM / SPLITK;

  STAGE_G(0, kbeg);
  __syncthreads();
  int cur = 0;
  for (int k0 = kbeg; k0 < kend; k0 += 32) {
    if (k0 + 32 < kend) STAGE_G(cur ^ 1, k0 + 32);

    bf16x8 af[4], bfr[4];
#pragma unroll
    for (int i = 0; i < 4; ++i)
      af[i] = *(const bf16x8*)&As[cur * 4096 + (wm + i * 16 + lrow) * 32 + quad * 8];
#pragma unroll
    for (int j = 0; j < 4; ++j)
      bfr[j] = *(const bf16x8*)&Bs[cur * 4096 + (wn + j * 16 + lrow) * 32 + quad * 8];
#pragma unroll
    for (int i = 0; i < 4; ++i)
#pragma unroll
      for (int j = 0; j < 4; ++j)
        acc[i][j] = __builtin_amdgcn_mfma_f32_16x16x32_bf16(af[i], bfr[j], acc[i][j], 0, 0, 0);

    __syncthreads();
    cur ^= 1;
  }

#pragma unroll
  for (int i = 0; i < 4; ++i) {
#pragma unroll
    for (int r = 0; r < 4; ++r) {
      int lm = wm + i * 16 + quad * 4 + r;
      int token = toks[lm];
      float* orow = out + (size_t)token * H_DIM;
#pragma unroll
      for (int j = 0; j < 4; ++j) {
        int gn = n0 + wn + j * 16 + lrow;
        atomicAdd(&orow[gn], acc[i][j][r]);
      }
    }
  }
}

extern "C" void kernel_launch(void* const* d_in, const int* in_sizes, int n_in,
                              void* d_out, int out_size, void* d_ws, size_t ws_size,
                              hipStream_t stream) {
  const float* x  = (const float*)d_in[0];
  const float* gw = (const float*)d_in[1];
  const float* w1 = (const float*)d_in[2];
  const float* w2 = (const float*)d_in[3];
  float* out = (float*)d_out;

  char* ws = (char*)d_ws;
  float* logits = (float*)ws;                                    // 256 KB
  int* idx = (int*)(ws + 262144);                                // 40 KB
  unsigned short* xb  = (unsigned short*)(ws + 303104);          // 16 MB
  unsigned short* w1t = (unsigned short*)(ws + 17080320);        // 64 MB
  unsigned short* w2t = (unsigned short*)(ws + 84189184);        // 64 MB
  unsigned short* hbuf = (unsigned short*)(ws + 151298048);      // 80 MB

  hipMemsetAsync(d_out, 0, (size_t)out_size * sizeof(float), stream);

  k_cvt_x<<<dim3(N_TOK * H_DIM / (256 * 8)), 256, 0, stream>>>(x, xb);
  k_transpose<<<dim3(F_DIM / 64, H_DIM / 64, E_NUM), 256, 0, stream>>>(w1, w1t, H_DIM, F_DIM);
  k_transpose<<<dim3(H_DIM / 64, F_DIM / 64, E_NUM), 256, 0, stream>>>(w2, w2t, F_DIM, H_DIM);
  k_gate<<<dim3(N_TOK / 4), 256, 0, stream>>>(x, gw, logits);
  k_topk<<<dim3(E_NUM), 1024, 0, stream>>>(logits, idx);
  k_gemm1<<<dim3(2560), 256, 0, stream>>>(xb, idx, w1t, hbuf);
  k_gemm2<<<dim3(2560), 256, 0, stream>>>(hbuf, idx, w2t, out);
}